// Round 11
// baseline (1092.414 us; speedup 1.0000x reference)
//
#include <hip/hip_runtime.h>
#include <cstdint>
#include <cstddef>

// Decoder_55654186222328 — MI355X, R19: fold_wiho -> MFMA GEMM (prep only).
// R18 post-mortem: decoder 999->995us — barrier removal worth ~4us. Decoder
// is now at its structural floor: 4 barriers = minimal for the phase dep
// graph; registers exactly full (128 VGPR + 128 AGPR x 2 waves = 512 pool);
// LDS full; all transcendentals/packs single-instruction. Remaining pool is
// prep+launch (~96us). fold_wiho was 256 blocks x 128-long SERIAL dependent
// f32 FMA chains; now 8 blocks of kv-style bf16 MFMA (wo staged TRANSPOSED,
// coalesced reads, one-time 8-way-conflict writes) in the same 52224 B LDS.
// Grid 1603 -> 1355. Decoder byte-identical to R18.
// Numerics: wih/wo bf16-rounded before a product already RNE'd to bf16
// (~2^-9 rel, same order as existing rounding; 5x absmax margin).

typedef short short8 __attribute__((ext_vector_type(8)));
typedef float f32x4 __attribute__((ext_vector_type(4)));

#define LOG2E 1.4426950408889634f
#define QSCALE 0.36067376022224085f /* log2(e)/4 */

__device__ __forceinline__ unsigned short f2bf(float f) {
  union { float f; unsigned int u; } v; v.f = f;
  unsigned int u = v.u;
  return (unsigned short)((u + 0x7fffu + ((u >> 16) & 1u)) >> 16);  // RNE
}
__device__ __forceinline__ unsigned cvtpk_bf16(float lo, float hi) {
  unsigned r;
  asm("v_cvt_pk_bf16_f32 %0, %1, %2" : "=v"(r) : "v"(lo), "v"(hi));
  return r;  // [15:0]=bf16(lo) [31:16]=bf16(hi); non-trans VOP3 (no hazard)
}
__device__ __forceinline__ float fexp2(float x) {
  return __builtin_amdgcn_exp2f(x);   // v_exp_f32, compiler-managed hazards
}
__device__ __forceinline__ float frcp(float x) {
  return __builtin_amdgcn_rcpf(x);    // v_rcp_f32, compiler-managed hazards
}
__device__ __forceinline__ float sigm(float x) {
  return frcp(1.f + fexp2(-LOG2E * x));
}
__device__ __forceinline__ float tanh_f(float x) {
  return 1.f - 2.f * frcp(1.f + fexp2(2.f * LOG2E * x));
}
__device__ __forceinline__ f32x4 splat4(float v) { f32x4 r = {v, v, v, v}; return r; }
__device__ __forceinline__ unsigned char f2fp8(float x) {
  return (unsigned char)__builtin_amdgcn_cvt_pk_fp8_f32(x, x, 0, false);
}
__device__ __forceinline__ f32x4 mfma_fp8(long a, long b, f32x4 c) {
  return __builtin_amdgcn_mfma_f32_16x16x32_fp8_fp8(a, b, c, 0, 0, 0);
}
__device__ __forceinline__ f32x4 mfma_bf16(short8 a, short8 b, f32x4 c) {
  return __builtin_amdgcn_mfma_f32_16x16x32_bf16(a, b, c, 0, 0, 0);
}

// ------------------------------------------------------------ prep (merged) --
// Block roles: [0,1024) kv-GEMM | [1024,1032) fold_wiho-GEMM |
// [1032,1320) convert | [1320,1355) fold_wq3b. All independent.
// K8[b][m][128] fp8; V8[b][d][512] fp8 (transposed, m-permuted within each
// 32-token chunk: slot s holds token pi(s), pi(8q+j)=4q+j (j<4) else
// 16+4q+(j-4)).
// kv LDS (two-phase weights): s_e bf16[64][136] @0 | s_w bf16[128][136]
// @17408. fold_wiho LDS: s_a bf16[64][136] @0 | s_b(=wo^T) bf16[128][136]
// @17408. Both 52224 B -> 3 blocks/CU.
__global__ __launch_bounds__(256) void prep_kernel(
    const float* __restrict__ emb, const float* __restrict__ wk,
    const float* __restrict__ bk, const float* __restrict__ wv,
    const float* __restrict__ bv,
    const float* __restrict__ w2, const float* __restrict__ whh,
    const float* __restrict__ wih, const float* __restrict__ wo,
    const float* __restrict__ wq, const float* __restrict__ w3,
    const float* __restrict__ b3, const float* __restrict__ bq,
    const float* __restrict__ bo, const float* __restrict__ bih,
    const float* __restrict__ bhh,
    unsigned char* __restrict__ K8, unsigned char* __restrict__ V8,
    unsigned short* __restrict__ W2, unsigned short* __restrict__ WHH,
    unsigned short* __restrict__ WIHO, unsigned short* __restrict__ WQ3,
    float* __restrict__ B4p, float* __restrict__ BQ3S) {
  extern __shared__ char smem[];
  const int tid = threadIdx.x;
  const int blk = blockIdx.x;

  if (blk < 1024) {  // ---- kv role: bf16 MFMA GEMM, two-phase weights ----
    unsigned short* s_e = (unsigned short*)smem;            // [64][136]
    unsigned short* s_w = (unsigned short*)(smem + 17408);  // [128][136]
    const int b = blk >> 3;
    const int m0 = (blk & 7) * 64;
    const int wave = tid >> 6;
    const int lane = tid & 63;
    const int quad = lane >> 4;
    const int l16 = lane & 15;

    // stage e + wk (pairs -> u32 writes; col even so 4B-aligned)
    for (int i = tid; i < 4096; i += 256) {
      int j = i * 2, row = j >> 7, col = j & 127;
      const float* p = emb + (size_t)(b * 512 + m0 + row) * 128 + col;
      *(unsigned*)(s_e + row * 136 + col) = cvtpk_bf16(p[0], p[1]);
    }
    for (int i = tid; i < 8192; i += 256) {
      int j = i * 2, row = j >> 7, col = j & 127;
      *(unsigned*)(s_w + row * 136 + col) =
          cvtpk_bf16(wk[row * 128 + col], wk[row * 128 + col + 1]);
    }
    __syncthreads();

    {  // K-phase: C[m][d] = e @ wk^T  (M64 N128 K128; wave = m-tile)
      const int mt = wave;
      short8 a8[4];
#pragma unroll
      for (int kt = 0; kt < 4; ++kt)
        a8[kt] = *(const short8*)(s_e + (mt * 16 + l16) * 136 + kt * 32 + quad * 8);
#pragma unroll
      for (int nt = 0; nt < 8; ++nt) {
        f32x4 acc = {0.f, 0.f, 0.f, 0.f};
#pragma unroll
        for (int kt = 0; kt < 4; ++kt) {
          short8 b8 = *(const short8*)(s_w + (nt * 16 + l16) * 136 + kt * 32 + quad * 8);
          acc = mfma_bf16(a8[kt], b8, acc);
        }
        const int d = nt * 16 + l16;
        const float bkd = bk[d];
#pragma unroll
        for (int r = 0; r < 4; ++r)
          K8[(size_t)(b * 512 + m0 + mt * 16 + quad * 4 + r) * 128 + d] =
              f2fp8(acc[r] + bkd);
      }
    }
    __syncthreads();  // K-phase reads of s_w done before wv overwrite
    for (int i = tid; i < 8192; i += 256) {
      int j = i * 2, row = j >> 7, col = j & 127;
      *(unsigned*)(s_w + row * 136 + col) =
          cvtpk_bf16(wv[row * 128 + col], wv[row * 128 + col + 1]);
    }
    __syncthreads();
    {  // V-phase: C[d][m] = wv @ e^T (M128 N64 K128; born transposed)
      const int dt0 = wave * 2;
#pragma unroll
      for (int dt = dt0; dt < dt0 + 2; ++dt) {
        short8 a8[4];
#pragma unroll
        for (int kt = 0; kt < 4; ++kt)
          a8[kt] = *(const short8*)(s_w + (dt * 16 + l16) * 136 + kt * 32 + quad * 8);
#pragma unroll
        for (int nt = 0; nt < 4; ++nt) {
          f32x4 acc = {0.f, 0.f, 0.f, 0.f};
#pragma unroll
          for (int kt = 0; kt < 4; ++kt) {
            short8 b8 = *(const short8*)(s_e + (nt * 16 + l16) * 136 + kt * 32 + quad * 8);
            acc = mfma_bf16(a8[kt], b8, acc);
          }
          const int m = m0 + nt * 16 + l16;
          const int ml = m & 31;
          const int sperm = (ml < 16) ? (((ml >> 2) << 3) | (ml & 3))
                                      : ((((ml - 16) >> 2) << 3) | ((ml - 16) & 3) | 4);
          const int mpos = (m & ~31) | sperm;
#pragma unroll
          for (int r = 0; r < 4; ++r) {
            const int d = dt * 16 + quad * 4 + r;
            V8[(size_t)(b * 128 + d) * 512 + mpos] = f2fp8(acc[r] + bv[d]);
          }
        }
      }
    }
  } else if (blk < 1032) {  // ---- fold WIHO via MFMA: WIHO = wih @ wo ----
    unsigned short* s_a = (unsigned short*)smem;            // wih [64][136]
    unsigned short* s_b = (unsigned short*)(smem + 17408);  // wo^T [128][136]
    const int r0 = (blk - 1024) * 64;
    const int wave = tid >> 6;
    const int lane = tid & 63;
    const int quad = lane >> 4;
    const int l16 = lane & 15;
    for (int i = tid; i < 4096; i += 256) {
      int j = i * 2, row = j >> 7, col = j & 127;
      const float* p = wih + (size_t)(r0 + row) * 128 + col;
      *(unsigned*)(s_a + row * 136 + col) = cvtpk_bf16(p[0], p[1]);
    }
    for (int i = tid; i < 8192; i += 256) {
      // s_b[d][2np..2np+1] = wo[2np][d], wo[2np+1][d]  (coalesced reads)
      int d = i & 127, np = i >> 7;
      *(unsigned*)(s_b + d * 136 + np * 2) =
          cvtpk_bf16(wo[(size_t)(np * 2) * 128 + d],
                     wo[(size_t)(np * 2 + 1) * 128 + d]);
    }
    __syncthreads();
    const int mt = wave;  // 4 row-tiles of 16 -> 64 rows/block
    short8 a8[4];
#pragma unroll
    for (int kt = 0; kt < 4; ++kt)
      a8[kt] = *(const short8*)(s_a + (mt * 16 + l16) * 136 + kt * 32 + quad * 8);
#pragma unroll
    for (int nt = 0; nt < 8; ++nt) {
      f32x4 acc = {0.f, 0.f, 0.f, 0.f};
#pragma unroll
      for (int kt = 0; kt < 4; ++kt) {
        short8 b8 = *(const short8*)(s_b + (nt * 16 + l16) * 136 + kt * 32 + quad * 8);
        acc = mfma_bf16(a8[kt], b8, acc);
      }
#pragma unroll
      for (int r = 0; r < 4; ++r)
        WIHO[(size_t)(r0 + mt * 16 + quad * 4 + r) * 128 + nt * 16 + l16] =
            f2bf(acc[r]);
    }
  } else if (blk < 1320) {  // ---- convert W2 + WHH -> bf16 ----
    int i = (blk - 1032) * 256 + tid;
    if (i < 8192) W2[i] = f2bf(w2[i]);
    else if (i < 73728) WHH[i - 8192] = f2bf(whh[i - 8192]);
  } else {  // ---- fold WQ3 + biases ----
    int i = (blk - 1320) * 256 + tid;
    if (i < 8192) {
      int n = i >> 6, k = i & 63;
      float acc = 0.f;
      for (int j = 0; j < 128; ++j) acc = fmaf(wq[n * 128 + j], w3[j * 64 + k], acc);
      WQ3[i] = f2bf(acc * QSCALE);
    } else if (i < 8704) {
      int r = i - 8192;
      float acc = bih[r] + bhh[r];
      for (int n = 0; n < 128; ++n) acc = fmaf(wih[r * 128 + n], bo[n], acc);
      B4p[r] = acc;
    } else if (i < 8832) {
      int n = i - 8704;
      float acc = bq[n];
      for (int j = 0; j < 128; ++j) acc = fmaf(wq[n * 128 + j], b3[j], acc);
      BQ3S[n] = acc * QSCALE;
    }
  }
}

// ---------------------------------------------------------------- decoder ----
// grid 256 = 128 b x 2 agent-halves (32 agents). 512 threads = 8 waves.
// LDS (162560 B, 1 block/CU):
//   sK    @0      fp8 [512][128] XOR-swz  65536   (persistent)
//   sV    @65536  fp8 [128][512] XOR-swz  65536   (persistent, transposed+pi)
//   bufV  @131072 u16 [32][136]            8704   \ ping-pong pair: one holds
//   bufU  @148480 u16 [32][136]            8704   / h(t), other h1|qf8|h(t+1)
//   bufB  @139776 u16 [32][136]            8704   (o)
//   zone  @157184 h2 u16 [32][72]          4608
//   maskb @162048 u8 [512]                  512
// Per-step barriers (4): P1|P3+P4|P6|P7+P0.  (R18 verbatim.)
__global__ __launch_bounds__(512, 2) void decoder_kernel(
    const float* __restrict__ cf, const int* __restrict__ cav,
    const float* __restrict__ hid,
    const float* __restrict__ ctx, const int* __restrict__ mav,
    const int* __restrict__ ntp,
    const float* __restrict__ w1, const float* __restrict__ b1,
    const float* __restrict__ b2,
    const unsigned char* __restrict__ K8, const unsigned char* __restrict__ V8,
    const unsigned short* __restrict__ W2, const unsigned short* __restrict__ WQ3,
    const unsigned short* __restrict__ WIHO, const unsigned short* __restrict__ WHH,
    const float* __restrict__ B4p, const float* __restrict__ BQ3S,
    const float* __restrict__ lnw, const float* __restrict__ lnb,
    float* __restrict__ out) {
  extern __shared__ char smem[];
  unsigned short* s_bufV = (unsigned short*)(smem + 131072);
  unsigned short* s_bufB = (unsigned short*)(smem + 139776);
  unsigned short* s_bufU = (unsigned short*)(smem + 148480);
  unsigned short* s_h2 = (unsigned short*)(smem + 157184);
  unsigned char* s_maskb = (unsigned char*)(smem + 162048);

  const int tid = threadIdx.x;
  const int wave = tid >> 6;
  const int lane = tid & 63;
  const int quad = lane >> 4;
  const int l16 = lane & 15;

  const int b = blockIdx.x & 127;
  const int a0 = (blockIdx.x >> 7) * 32;
  const int T = *ntp;
  const f32x4 zero4 = {0.f, 0.f, 0.f, 0.f};
  const long kOnes = 0x3838383838383838L;  // fp8 e4m3 1.0 x8

  // ---- preload persistent K/V into LDS with XOR swizzle ----
  {
    const unsigned long long* Kg = (const unsigned long long*)(K8 + (size_t)b * 65536);
    for (int i = tid; i < 8192; i += 512) {
      int tok = i >> 4, seg = i & 15;
      *(unsigned long long*)(smem + tok * 128 + ((seg * 8) ^ ((tok & 15) * 8))) =
          Kg[(size_t)tok * 16 + seg];
    }
    const unsigned long long* Vg = (const unsigned long long*)(V8 + (size_t)b * 65536);
    for (int i = tid; i < 8192; i += 512) {
      int d = i >> 6, seg = i & 63;
      *(unsigned long long*)(smem + 65536 + d * 512 + ((seg * 8) ^ ((d & 15) * 8))) =
          Vg[(size_t)d * 64 + seg];
    }
  }
  // ---- init ----
  s_maskb[tid] = mav[b * 512 + tid] ? 1 : 0;
  {  // h0 -> U (step 0's h-buffer) — recurrent init: software RNE
    int idx = tid * 8;
    int a = idx >> 7, n0 = idx & 127;
    const float* hp = hid + (size_t)(b * 64 + a0 + a) * 128 + n0;
    short8 v;
#pragma unroll
    for (int j = 0; j < 8; ++j) v[j] = (short)f2bf(hp[j]);
    *(short8*)(s_bufU + a * 136 + n0) = v;
  }
  float c_reg[2][4], avl[2][4];
#pragma unroll
  for (int mt = 0; mt < 2; ++mt)
#pragma unroll
    for (int r = 0; r < 4; ++r) {
      int a = mt * 16 + quad * 4 + r;
      c_reg[mt][r] = ctx[(size_t)(b * 64 + a0 + a) * 128 + wave * 16 + l16];
      avl[mt][r] = (cav[b * 64 + a0 + a] != 0) ? 1.f : 0.f;
    }

  // ---- persistent register-cached weights (step-invariant) ----
  const int wrow = wave * 16 + l16;
  short8 rIH[4][4], rHH[4][4];
#pragma unroll
  for (int kt = 0; kt < 4; ++kt)
#pragma unroll
    for (int g = 0; g < 4; ++g) {
      rIH[kt][g] = *(const short8*)(WIHO + ((g * 128 + wrow) * 128 + kt * 32 + quad * 8));
      rHH[kt][g] = *(const short8*)(WHH + ((g * 128 + wrow) * 128 + kt * 32 + quad * 8));
    }
  short8 rWQ3[2];
#pragma unroll
  for (int kt = 0; kt < 2; ++kt)
    rWQ3[kt] = *(const short8*)(WQ3 + (wrow * 64 + kt * 32 + quad * 8));
  float rB4[4];
#pragma unroll
  for (int g = 0; g < 4; ++g) rB4[g] = B4p[g * 128 + wrow];
  const float rBQ3 = BQ3S[wrow];
  const float rB2 = b2[(wave & 3) * 16 + l16];

  // ---- fused-P7/P0 per-thread constants + register state ----
  const int p7_o = tid >> 3, p7_sub = tid & 7;
  const int p7_a = p7_o >> 1, p7_oi = p7_o & 1;
  const float mylnb = lnb[p7_oi];
  float myst = cf[(size_t)(b * 64 + a0 + p7_a) * 2 + p7_oi];

  __syncthreads();

  // per-lane mask flags: bit i set when token i*16+l16 is NOT available.
  unsigned mflags = 0;
#pragma unroll
  for (int i = 0; i < 32; ++i)
    if (!s_maskb[i * 16 + l16]) mflags |= (1u << i);

  // ---- initial h1 from initial state -> V (step 0's xb) ----
  {
    float other = __shfl_xor(myst, 8);
    float st0 = p7_oi ? other : myst;
    float st1 = p7_oi ? myst : other;
    int a = tid >> 4, n0 = (tid & 15) * 8;
    const float* wp = w1 + n0 * 2;
    const float* bp = b1 + n0;
    float x[8];
#pragma unroll
    for (int j = 0; j < 8; ++j)
      x[j] = fmaxf(fmaf(wp[j * 2], st0, fmaf(wp[j * 2 + 1], st1, bp[j])), 0.f);
    union { short8 s; unsigned u[4]; } v;
#pragma unroll
    for (int j = 0; j < 4; ++j) v.u[j] = cvtpk_bf16(x[j * 2], x[j * 2 + 1]);
    *(short8*)(s_bufV + a * 136 + n0) = v.s;
  }
  __syncthreads();

#pragma unroll 1
  for (int t = 0; t < T; ++t) {
    unsigned short* hb = (t & 1) ? s_bufV : s_bufU;  // holds h(t)
    unsigned short* xb = (t & 1) ? s_bufU : s_bufV;  // h1 | qf8 | h(t+1)

    // ---- P1: h2 = relu(h1 @ w2^T + b2)  M32 N64 K128 -> zone ----
    {
      int mt = wave >> 2, nt = wave & 3;
      f32x4 acc = splat4(rB2);
#pragma unroll
      for (int kt = 0; kt < 4; ++kt) {
        short8 a8 = *(const short8*)(xb + (mt * 16 + l16) * 136 + kt * 32 + quad * 8);
        short8 b8 = *(const short8*)(W2 + ((nt * 16 + l16) * 128 + kt * 32 + quad * 8));
        acc = mfma_bf16(a8, b8, acc);
      }
      unsigned pk01 = cvtpk_bf16(fmaxf(acc[0], 0.f), fmaxf(acc[1], 0.f));
      unsigned pk23 = cvtpk_bf16(fmaxf(acc[2], 0.f), fmaxf(acc[3], 0.f));
      unsigned short* hbp = s_h2 + (mt * 16 + quad * 4) * 72 + nt * 16 + l16;
      hbp[0] = (unsigned short)pk01;
      hbp[72] = (unsigned short)(pk01 >> 16);
      hbp[144] = (unsigned short)pk23;
      hbp[216] = (unsigned short)(pk23 >> 16);
    }
    __syncthreads();

    // ---- P3: q = h2 @ WQ3^T + bq3 -> fp8 in xb bytes (h1 dead) ----
    // wave nt==h produces exactly head h's q-columns -> no barrier before P4.
    unsigned char* s_q8 = (unsigned char*)xb;
    {
#pragma unroll
      for (int mt = 0; mt < 2; ++mt) {
        f32x4 acc = splat4(rBQ3);
#pragma unroll
        for (int kt = 0; kt < 2; ++kt) {
          short8 a8 = *(const short8*)(s_h2 + (mt * 16 + l16) * 72 + kt * 32 + quad * 8);
          acc = mfma_bf16(a8, rWQ3[kt], acc);
        }
#pragma unroll
        for (int r = 0; r < 4; ++r)
          s_q8[(mt * 16 + quad * 4 + r) * 136 + wave * 16 + l16] = f2fp8(acc[r]);
      }
    }
    __asm__ volatile("s_waitcnt lgkmcnt(0)" ::: "memory");
    __builtin_amdgcn_sched_barrier(0);

    // ---- P4: attention — swapped-operand MFMA, P in registers, prefetched ----
    {
      const int h = wave;
      const char* sKb = (const char*)smem;
      const char* sVrow = (const char*)(smem + 65536) + (h * 16 + l16) * 512;
      long qA[2];
#pragma unroll
      for (int mt = 0; mt < 2; ++mt)
        qA[mt] = (quad < 2)
                     ? *(const long*)(s_q8 + (mt * 16 + l16) * 136 + h * 16 + quad * 8)
                     : (quad == 2 ? 0xF8L : 0L);  // byte0 = fp8 -256
      const int koff = (h * 16 + quad * 8) ^ (l16 * 8);
      f32x4 O[2], L4[2];
      O[0] = zero4; O[1] = zero4; L4[0] = zero4; L4[1] = zero4;
      // prefetch chunk 0
      long vA_c = *(const long*)(sVrow + ((quad * 8) ^ (l16 * 8)));
      long kB_c0 = 0L, kB_c1 = 0L;
      if (quad < 2) {
        kB_c0 = *(const long*)(sKb + (size_t)l16 * 128 + koff);
        kB_c1 = *(const long*)(sKb + (size_t)(16 + l16) * 128 + koff);
      }
#pragma unroll 4
      for (int c = 0; c < 16; ++c) {
        long vA_n = 0L, kB_n0 = 0L, kB_n1 = 0L;
        if (c < 15) {
          vA_n = *(const long*)(sVrow + (((c + 1) * 32 + quad * 8) ^ (l16 * 8)));
          if (quad < 2) {
            kB_n0 = *(const long*)(sKb + (size_t)((c + 1) * 32 + l16) * 128 + koff);
            kB_n1 = *(const long*)(sKb + (size_t)((c + 1) * 32 + 16 + l16) * 128 + koff);
          }
        }
        long kB0 = kB_c0, kB1 = kB_c1;
        if (quad == 2) {
          kB0 = ((mflags >> (c * 2)) & 1u) ? 0x38L : 0L;      // fp8 1.0 flag
          kB1 = ((mflags >> (c * 2 + 1)) & 1u) ? 0x38L : 0L;
        }
        __builtin_amdgcn_s_setprio(1);
        f32x4 S2[2][2];
        S2[0][0] = mfma_fp8(kB0, qA[0], zero4);
        S2[0][1] = mfma_fp8(kB0, qA[1], zero4);
        S2[1][0] = mfma_fp8(kB1, qA[0], zero4);
        S2[1][1] = mfma_fp8(kB1, qA[1], zero4);
        __builtin_amdgcn_s_setprio(0);
        long pB[2];
#pragma unroll
        for (int mt = 0; mt < 2; ++mt) {
          unsigned w0 = (unsigned)__builtin_amdgcn_cvt_pk_fp8_f32(
              fexp2(S2[0][mt][0]), fexp2(S2[0][mt][1]), 0, false);
          w0 = (unsigned)__builtin_amdgcn_cvt_pk_fp8_f32(
              fexp2(S2[0][mt][2]), fexp2(S2[0][mt][3]), (int)w0, true);
          unsigned w1v = (unsigned)__builtin_amdgcn_cvt_pk_fp8_f32(
              fexp2(S2[1][mt][0]), fexp2(S2[1][mt][1]), 0, false);
          w1v = (unsigned)__builtin_amdgcn_cvt_pk_fp8_f32(
              fexp2(S2[1][mt][2]), fexp2(S2[1][mt][3]), (int)w1v, true);
          pB[mt] = (long)(((unsigned long long)w1v << 32) | (unsigned long long)w0);
        }
        __builtin_amdgcn_s_setprio(1);
        O[0] = mfma_fp8(vA_c, pB[0], O[0]);     // O^T: rows d-local, cols a
        L4[0] = mfma_fp8(kOnes, pB[0], L4[0]);
        O[1] = mfma_fp8(vA_c, pB[1], O[1]);
        L4[1] = mfma_fp8(kOnes, pB[1], L4[1]);
        __builtin_amdgcn_s_setprio(0);
        vA_c = vA_n; kB_c0 = kB_n0; kB_c1 = kB_n1;
      }
      // o -> bufB (within-step pack); O^T: d = h*16+quad*4+r, a = mt*16+l16
#pragma unroll
      for (int mt = 0; mt < 2; ++mt) {
        float o0 = O[mt][0] * frcp(L4[mt][0]);
        float o1 = O[mt][1] * frcp(L4[mt][1]);
        float o2 = O[mt][2] * frcp(L4[mt][2]);
        float o3 = O[mt][3] * frcp(L4[mt][3]);
        unsigned long long ow =
            ((unsigned long long)cvtpk_bf16(o2, o3) << 32) | cvtpk_bf16(o0, o1);
        *(unsigned long long*)(s_bufB + (mt * 16 + l16) * 136 + h * 16 + quad * 4) = ow;
      }
    }
    __syncthreads();

    // ---- P6: LSTM gates; reads h from hb + o from bufB, writes h(t+1) to
    // xb (qf8 dead; disjoint from all P6 reads -> no mid-barrier). ----
    {
      const int ni = wave;
      f32x4 gi[2], gf[2], gg[2], go[2];
#pragma unroll
      for (int mt = 0; mt < 2; ++mt) {
        gi[mt] = splat4(rB4[0]);
        gf[mt] = splat4(rB4[1]);
        gg[mt] = splat4(rB4[2]);
        go[mt] = splat4(rB4[3]);
      }
      __builtin_amdgcn_s_setprio(1);
#pragma unroll
      for (int kt = 0; kt < 4; ++kt)
#pragma unroll
        for (int mt = 0; mt < 2; ++mt) {
          short8 a8 = *(const short8*)(s_bufB + (mt * 16 + l16) * 136 + kt * 32 + quad * 8);
          gi[mt] = mfma_bf16(a8, rIH[kt][0], gi[mt]);
          gf[mt] = mfma_bf16(a8, rIH[kt][1], gf[mt]);
          gg[mt] = mfma_bf16(a8, rIH[kt][2], gg[mt]);
          go[mt] = mfma_bf16(a8, rIH[kt][3], go[mt]);
        }
#pragma unroll
      for (int kt = 0; kt < 4; ++kt)
#pragma unroll
        for (int mt = 0; mt < 2; ++mt) {
          short8 a8 = *(const short8*)(hb + (mt * 16 + l16) * 136 + kt * 32 + quad * 8);
          gi[mt] = mfma_bf16(a8, rHH[kt][0], gi[mt]);
          gf[mt] = mfma_bf16(a8, rHH[kt][1], gf[mt]);
          gg[mt] = mfma_bf16(a8, rHH[kt][2], gg[mt]);
          go[mt] = mfma_bf16(a8, rHH[kt][3], go[mt]);
        }
      __builtin_amdgcn_s_setprio(0);
#pragma unroll
      for (int mt = 0; mt < 2; ++mt)
#pragma unroll
        for (int r = 0; r < 4; ++r) {
          float iv = sigm(gi[mt][r]);
          float fv = sigm(gf[mt][r]);
          float gv = tanh_f(gg[mt][r]);
          float ov = sigm(go[mt][r]);
          float cn = fmaf(fv, c_reg[mt][r], iv * gv);
          float hv = ov * tanh_f(cn);
          int arow = mt * 16 + quad * 4 + r;
          float av = avl[mt][r];
          union { unsigned int u; float f; } ho;
          ho.u = ((unsigned int)hb[arow * 136 + ni * 16 + l16]) << 16;
          c_reg[mt][r] = av * cn + (1.f - av) * c_reg[mt][r];
          float hn = av * hv + (1.f - av) * ho.f;
          xb[arow * 136 + ni * 16 + l16] = f2bf(hn);  // recurrent: RNE
        }
    }
    __syncthreads();

    // ---- P7+P0 fused: state += h @ lin_w^T + lin_b; emit; next h1 ----
    {
      const unsigned short* hp = xb + p7_a * 136 + p7_sub * 16;
      const float* lw = lnw + p7_oi * 128 + p7_sub * 16;
      short8 h0 = *(const short8*)hp;
      short8 h1 = *(const short8*)(hp + 8);
      float acc = 0.f;
#pragma unroll
      for (int k = 0; k < 8; ++k) {
        union { unsigned int u; float f; } hv;
        hv.u = ((unsigned int)(unsigned short)h0[k]) << 16;
        acc = fmaf(hv.f, lw[k], acc);
      }
#pragma unroll
      for (int k = 0; k < 8; ++k) {
        union { unsigned int u; float f; } hv;
        hv.u = ((unsigned int)(unsigned short)h1[k]) << 16;
        acc = fmaf(hv.f, lw[8 + k], acc);
      }
      acc += __shfl_xor(acc, 4);
      acc += __shfl_xor(acc, 2);
      acc += __shfl_xor(acc, 1);
      float ns = myst + acc + mylnb;
      myst = ns;
      if (p7_sub == 0)
        out[((size_t)(b * 64 + a0 + p7_a) * T + t) * 2 + p7_oi] = ns;
      // P0: h1(t+1) = relu(state @ w1^T + b1) -> hb (h(t) dead)
      float other = __shfl_xor(ns, 8);
      float st0 = p7_oi ? other : ns;
      float st1 = p7_oi ? ns : other;
      int a = tid >> 4, n0 = (tid & 15) * 8;
      const float* wp = w1 + n0 * 2;
      const float* bp = b1 + n0;
      float x[8];
#pragma unroll
      for (int j = 0; j < 8; ++j)
        x[j] = fmaxf(fmaf(wp[j * 2], st0, fmaf(wp[j * 2 + 1], st1, bp[j])), 0.f);
      union { short8 s; unsigned u[4]; } v;
#pragma unroll
      for (int j = 0; j < 4; ++j) v.u[j] = cvtpk_bf16(x[j * 2], x[j * 2 + 1]);
      *(short8*)(hb + a * 136 + n0) = v.s;
    }
    __syncthreads();
  }
}

// ---------------------------------------------------------------- launch ----
extern "C" void kernel_launch(void* const* d_in, const int* in_sizes, int n_in,
                              void* d_out, int out_size, void* d_ws, size_t ws_size,
                              hipStream_t stream) {
  (void)in_sizes; (void)n_in; (void)out_size; (void)ws_size;
  const float* cf = (const float*)d_in[0];
  const int* cav = (const int*)d_in[1];
  const float* hid = (const float*)d_in[2];
  const float* ctx = (const float*)d_in[3];
  const float* emb = (const float*)d_in[4];
  const int* mav = (const int*)d_in[5];
  const int* ntp = (const int*)d_in[6];
  const float* w1 = (const float*)d_in[7];
  const float* b1 = (const float*)d_in[8];
  const float* w2 = (const float*)d_in[9];
  const float* b2 = (const float*)d_in[10];
  const float* w3 = (const float*)d_in[11];
  const float* b3 = (const float*)d_in[12];
  const float* wq = (const float*)d_in[13];
  const float* bq = (const float*)d_in[14];
  const float* wk = (const float*)d_in[15];
  const float* bk = (const float*)d_in[16];
  const float* wv = (const float*)d_in[17];
  const float* bv = (const float*)d_in[18];
  const float* wo = (const float*)d_in[19];
  const float* bo = (const float*)d_in[20];
  const float* wih = (const float*)d_in[21];  // w_ih
  const float* whh = (const float*)d_in[22];  // w_hh
  const float* bih = (const float*)d_in[23];  // b_ih
  const float* bhh = (const float*)d_in[24];  // b_hh
  const float* lnw = (const float*)d_in[25];
  const float* lnb = (const float*)d_in[26];

  char* ws = (char*)d_ws;
  unsigned char* K8 = (unsigned char*)(ws + 0);         // 8,388,608
  unsigned char* V8 = (unsigned char*)(ws + 8388608);   // 8,388,608
  unsigned short* W2s = (unsigned short*)(ws + 16777216);   // 16,384 B
  unsigned short* WQ3s = (unsigned short*)(ws + 16793600);  // 16,384 B
  unsigned short* WIHOs = (unsigned short*)(ws + 16809984); // 131,072 B
  unsigned short* WHHs = (unsigned short*)(ws + 16941056);  // 131,072 B
  float* B4p = (float*)(ws + 17072128);                     // 2,048 B
  float* BQ3S = (float*)(ws + 17074176);                    // 512 B

  (void)hipFuncSetAttribute((const void*)prep_kernel,
                            hipFuncAttributeMaxDynamicSharedMemorySize, 52224);
  (void)hipFuncSetAttribute((const void*)decoder_kernel,
                            hipFuncAttributeMaxDynamicSharedMemorySize, 162560);

  prep_kernel<<<1355, 256, 52224, stream>>>(
      emb, wk, bk, wv, bv, w2, whh, wih, wo, wq, w3, b3, bq, bo, bih, bhh,
      K8, V8, W2s, WHHs, WIHOs, WQ3s, B4p, BQ3S);
  decoder_kernel<<<256, 512, 162560, stream>>>(
      cf, cav, hid, ctx, mav, ntp, w1, b1, b2, K8, V8, W2s, WQ3s, WIHOs, WHHs,
      B4p, BQ3S, lnw, lnb, (float*)d_out);
}

// Round 12
// 1078.067 us; speedup vs baseline: 1.0133x; 1.0133x over previous
//
#include <hip/hip_runtime.h>
#include <cstdint>
#include <cstddef>

// Decoder_55654186222328 — MI355X, R20: prep single-round (512-thr kv blocks).
// R19 post-mortem: total unchanged (1092) — fold_wiho wasn't the prep tail;
// the kv role's 2-round dispatch (1024 blocks @ 3/CU) was. R20 widens kv to
// 512 threads / 128 tokens per block: 512 blocks @ 69632 B LDS = 2 blocks/CU
// -> ALL kv blocks resident in one round. Small roles rescaled to 512 thr
// (wiho: (mt, n-half) wave split; convert 144 blks; fold 18 blks). Grid
// 1355 -> 682. Per-output tile math identical (same kt order, same inputs)
// -> bitwise-identical workspace outputs. Decoder byte-identical to R18/R19
// (996us; latency-bound at 2 waves/SIMD; 16-wave rewrite rejected: weight
// cache can't split without a 32-128KB exchange buffer that doesn't exist).

typedef short short8 __attribute__((ext_vector_type(8)));
typedef float f32x4 __attribute__((ext_vector_type(4)));

#define LOG2E 1.4426950408889634f
#define QSCALE 0.36067376022224085f /* log2(e)/4 */

__device__ __forceinline__ unsigned short f2bf(float f) {
  union { float f; unsigned int u; } v; v.f = f;
  unsigned int u = v.u;
  return (unsigned short)((u + 0x7fffu + ((u >> 16) & 1u)) >> 16);  // RNE
}
__device__ __forceinline__ unsigned cvtpk_bf16(float lo, float hi) {
  unsigned r;
  asm("v_cvt_pk_bf16_f32 %0, %1, %2" : "=v"(r) : "v"(lo), "v"(hi));
  return r;  // [15:0]=bf16(lo) [31:16]=bf16(hi); non-trans VOP3 (no hazard)
}
__device__ __forceinline__ float fexp2(float x) {
  return __builtin_amdgcn_exp2f(x);   // v_exp_f32, compiler-managed hazards
}
__device__ __forceinline__ float frcp(float x) {
  return __builtin_amdgcn_rcpf(x);    // v_rcp_f32, compiler-managed hazards
}
__device__ __forceinline__ float sigm(float x) {
  return frcp(1.f + fexp2(-LOG2E * x));
}
__device__ __forceinline__ float tanh_f(float x) {
  return 1.f - 2.f * frcp(1.f + fexp2(2.f * LOG2E * x));
}
__device__ __forceinline__ f32x4 splat4(float v) { f32x4 r = {v, v, v, v}; return r; }
__device__ __forceinline__ unsigned char f2fp8(float x) {
  return (unsigned char)__builtin_amdgcn_cvt_pk_fp8_f32(x, x, 0, false);
}
__device__ __forceinline__ f32x4 mfma_fp8(long a, long b, f32x4 c) {
  return __builtin_amdgcn_mfma_f32_16x16x32_fp8_fp8(a, b, c, 0, 0, 0);
}
__device__ __forceinline__ f32x4 mfma_bf16(short8 a, short8 b, f32x4 c) {
  return __builtin_amdgcn_mfma_f32_16x16x32_bf16(a, b, c, 0, 0, 0);
}

// ------------------------------------------------------------ prep (merged) --
// 512 threads/block. Roles: [0,512) kv-GEMM (b = blk>>2, m0 = (blk&3)*128) |
// [512,520) fold_wiho-GEMM | [520,664) convert | [664,682) fold_wq3b.
// K8[b][m][128] fp8; V8[b][d][512] fp8 (transposed, m-permuted within each
// 32-token chunk: slot s holds token pi(s), pi(8q+j)=4q+j (j<4) else
// 16+4q+(j-4)).
// kv LDS (two-phase weights): s_e bf16[128][136] @0 (34816) |
// s_w bf16[128][136] @34816 (34816). Total 69632 B -> 2 blocks/CU ->
// all 512 kv blocks resident in ONE round.
__global__ __launch_bounds__(512) void prep_kernel(
    const float* __restrict__ emb, const float* __restrict__ wk,
    const float* __restrict__ bk, const float* __restrict__ wv,
    const float* __restrict__ bv,
    const float* __restrict__ w2, const float* __restrict__ whh,
    const float* __restrict__ wih, const float* __restrict__ wo,
    const float* __restrict__ wq, const float* __restrict__ w3,
    const float* __restrict__ b3, const float* __restrict__ bq,
    const float* __restrict__ bo, const float* __restrict__ bih,
    const float* __restrict__ bhh,
    unsigned char* __restrict__ K8, unsigned char* __restrict__ V8,
    unsigned short* __restrict__ W2, unsigned short* __restrict__ WHH,
    unsigned short* __restrict__ WIHO, unsigned short* __restrict__ WQ3,
    float* __restrict__ B4p, float* __restrict__ BQ3S) {
  extern __shared__ char smem[];
  const int tid = threadIdx.x;
  const int blk = blockIdx.x;

  if (blk < 512) {  // ---- kv role: bf16 MFMA GEMM, two-phase weights ----
    unsigned short* s_e = (unsigned short*)smem;            // [128][136]
    unsigned short* s_w = (unsigned short*)(smem + 34816);  // [128][136]
    const int b = blk >> 2;
    const int m0 = (blk & 3) * 128;
    const int wave = tid >> 6;
    const int lane = tid & 63;
    const int quad = lane >> 4;
    const int l16 = lane & 15;

    // stage e + wk (pairs -> u32 writes; col even so 4B-aligned)
    for (int i = tid; i < 8192; i += 512) {
      int j = i * 2, row = j >> 7, col = j & 127;
      const float* p = emb + (size_t)(b * 512 + m0 + row) * 128 + col;
      *(unsigned*)(s_e + row * 136 + col) = cvtpk_bf16(p[0], p[1]);
    }
    for (int i = tid; i < 8192; i += 512) {
      int j = i * 2, row = j >> 7, col = j & 127;
      *(unsigned*)(s_w + row * 136 + col) =
          cvtpk_bf16(wk[row * 128 + col], wk[row * 128 + col + 1]);
    }
    __syncthreads();

    {  // K-phase: C[m][d] = e @ wk^T  (M128 N128 K128; wave = m-tile)
      const int mt = wave;
      short8 a8[4];
#pragma unroll
      for (int kt = 0; kt < 4; ++kt)
        a8[kt] = *(const short8*)(s_e + (mt * 16 + l16) * 136 + kt * 32 + quad * 8);
#pragma unroll
      for (int nt = 0; nt < 8; ++nt) {
        f32x4 acc = {0.f, 0.f, 0.f, 0.f};
#pragma unroll
        for (int kt = 0; kt < 4; ++kt) {
          short8 b8 = *(const short8*)(s_w + (nt * 16 + l16) * 136 + kt * 32 + quad * 8);
          acc = mfma_bf16(a8[kt], b8, acc);
        }
        const int d = nt * 16 + l16;
        const float bkd = bk[d];
#pragma unroll
        for (int r = 0; r < 4; ++r)
          K8[(size_t)(b * 512 + m0 + mt * 16 + quad * 4 + r) * 128 + d] =
              f2fp8(acc[r] + bkd);
      }
    }
    __syncthreads();  // K-phase reads of s_w done before wv overwrite
    for (int i = tid; i < 8192; i += 512) {
      int j = i * 2, row = j >> 7, col = j & 127;
      *(unsigned*)(s_w + row * 136 + col) =
          cvtpk_bf16(wv[row * 128 + col], wv[row * 128 + col + 1]);
    }
    __syncthreads();
    {  // V-phase: C[d][m] = wv @ e^T (M128 N128 K128; born transposed)
      const int dt = wave;
      short8 a8[4];
#pragma unroll
      for (int kt = 0; kt < 4; ++kt)
        a8[kt] = *(const short8*)(s_w + (dt * 16 + l16) * 136 + kt * 32 + quad * 8);
#pragma unroll
      for (int nt = 0; nt < 8; ++nt) {
        f32x4 acc = {0.f, 0.f, 0.f, 0.f};
#pragma unroll
        for (int kt = 0; kt < 4; ++kt) {
          short8 b8 = *(const short8*)(s_e + (nt * 16 + l16) * 136 + kt * 32 + quad * 8);
          acc = mfma_bf16(a8[kt], b8, acc);
        }
        const int m = m0 + nt * 16 + l16;
        const int ml = m & 31;
        const int sperm = (ml < 16) ? (((ml >> 2) << 3) | (ml & 3))
                                    : ((((ml - 16) >> 2) << 3) | ((ml - 16) & 3) | 4);
        const int mpos = (m & ~31) | sperm;
#pragma unroll
        for (int r = 0; r < 4; ++r) {
          const int d = dt * 16 + quad * 4 + r;
          V8[(size_t)(b * 128 + d) * 512 + mpos] = f2fp8(acc[r] + bv[d]);
        }
      }
    }
  } else if (blk < 520) {  // ---- fold WIHO via MFMA: WIHO = wih @ wo ----
    unsigned short* s_a = (unsigned short*)smem;            // wih [64][136]
    unsigned short* s_b = (unsigned short*)(smem + 34816);  // wo^T [128][136]
    const int r0 = (blk - 512) * 64;
    const int wave = tid >> 6;
    const int lane = tid & 63;
    const int quad = lane >> 4;
    const int l16 = lane & 15;
    for (int i = tid; i < 4096; i += 512) {
      int j = i * 2, row = j >> 7, col = j & 127;
      const float* p = wih + (size_t)(r0 + row) * 128 + col;
      *(unsigned*)(s_a + row * 136 + col) = cvtpk_bf16(p[0], p[1]);
    }
    for (int i = tid; i < 8192; i += 512) {
      // s_b[d][2np..2np+1] = wo[2np][d], wo[2np+1][d]  (coalesced reads)
      int d = i & 127, np = i >> 7;
      *(unsigned*)(s_b + d * 136 + np * 2) =
          cvtpk_bf16(wo[(size_t)(np * 2) * 128 + d],
                     wo[(size_t)(np * 2 + 1) * 128 + d]);
    }
    __syncthreads();
    const int mt = wave & 3;        // 4 row-tiles of 16 -> 64 rows/block
    const int nh = wave >> 2;       // n-half: nt in [nh*4, nh*4+4)
    short8 a8[4];
#pragma unroll
    for (int kt = 0; kt < 4; ++kt)
      a8[kt] = *(const short8*)(s_a + (mt * 16 + l16) * 136 + kt * 32 + quad * 8);
#pragma unroll
    for (int ntl = 0; ntl < 4; ++ntl) {
      const int nt = nh * 4 + ntl;
      f32x4 acc = {0.f, 0.f, 0.f, 0.f};
#pragma unroll
      for (int kt = 0; kt < 4; ++kt) {
        short8 b8 = *(const short8*)(s_b + (nt * 16 + l16) * 136 + kt * 32 + quad * 8);
        acc = mfma_bf16(a8[kt], b8, acc);
      }
#pragma unroll
      for (int r = 0; r < 4; ++r)
        WIHO[(size_t)(r0 + mt * 16 + quad * 4 + r) * 128 + nt * 16 + l16] =
            f2bf(acc[r]);
    }
  } else if (blk < 664) {  // ---- convert W2 + WHH -> bf16 ----
    int i = (blk - 520) * 512 + tid;
    if (i < 8192) W2[i] = f2bf(w2[i]);
    else if (i < 73728) WHH[i - 8192] = f2bf(whh[i - 8192]);
  } else {  // ---- fold WQ3 + biases ----
    int i = (blk - 664) * 512 + tid;
    if (i < 8192) {
      int n = i >> 6, k = i & 63;
      float acc = 0.f;
      for (int j = 0; j < 128; ++j) acc = fmaf(wq[n * 128 + j], w3[j * 64 + k], acc);
      WQ3[i] = f2bf(acc * QSCALE);
    } else if (i < 8704) {
      int r = i - 8192;
      float acc = bih[r] + bhh[r];
      for (int n = 0; n < 128; ++n) acc = fmaf(wih[r * 128 + n], bo[n], acc);
      B4p[r] = acc;
    } else if (i < 8832) {
      int n = i - 8704;
      float acc = bq[n];
      for (int j = 0; j < 128; ++j) acc = fmaf(wq[n * 128 + j], b3[j], acc);
      BQ3S[n] = acc * QSCALE;
    }
  }
}

// ---------------------------------------------------------------- decoder ----
// grid 256 = 128 b x 2 agent-halves (32 agents). 512 threads = 8 waves.
// LDS (162560 B, 1 block/CU):
//   sK    @0      fp8 [512][128] XOR-swz  65536   (persistent)
//   sV    @65536  fp8 [128][512] XOR-swz  65536   (persistent, transposed+pi)
//   bufV  @131072 u16 [32][136]            8704   \ ping-pong pair: one holds
//   bufU  @148480 u16 [32][136]            8704   / h(t), other h1|qf8|h(t+1)
//   bufB  @139776 u16 [32][136]            8704   (o)
//   zone  @157184 h2 u16 [32][72]          4608
//   maskb @162048 u8 [512]                  512
// Per-step barriers (4): P1|P3+P4|P6|P7+P0.  (R18/R19 verbatim.)
__global__ __launch_bounds__(512, 2) void decoder_kernel(
    const float* __restrict__ cf, const int* __restrict__ cav,
    const float* __restrict__ hid,
    const float* __restrict__ ctx, const int* __restrict__ mav,
    const int* __restrict__ ntp,
    const float* __restrict__ w1, const float* __restrict__ b1,
    const float* __restrict__ b2,
    const unsigned char* __restrict__ K8, const unsigned char* __restrict__ V8,
    const unsigned short* __restrict__ W2, const unsigned short* __restrict__ WQ3,
    const unsigned short* __restrict__ WIHO, const unsigned short* __restrict__ WHH,
    const float* __restrict__ B4p, const float* __restrict__ BQ3S,
    const float* __restrict__ lnw, const float* __restrict__ lnb,
    float* __restrict__ out) {
  extern __shared__ char smem[];
  unsigned short* s_bufV = (unsigned short*)(smem + 131072);
  unsigned short* s_bufB = (unsigned short*)(smem + 139776);
  unsigned short* s_bufU = (unsigned short*)(smem + 148480);
  unsigned short* s_h2 = (unsigned short*)(smem + 157184);
  unsigned char* s_maskb = (unsigned char*)(smem + 162048);

  const int tid = threadIdx.x;
  const int wave = tid >> 6;
  const int lane = tid & 63;
  const int quad = lane >> 4;
  const int l16 = lane & 15;

  const int b = blockIdx.x & 127;
  const int a0 = (blockIdx.x >> 7) * 32;
  const int T = *ntp;
  const f32x4 zero4 = {0.f, 0.f, 0.f, 0.f};
  const long kOnes = 0x3838383838383838L;  // fp8 e4m3 1.0 x8

  // ---- preload persistent K/V into LDS with XOR swizzle ----
  {
    const unsigned long long* Kg = (const unsigned long long*)(K8 + (size_t)b * 65536);
    for (int i = tid; i < 8192; i += 512) {
      int tok = i >> 4, seg = i & 15;
      *(unsigned long long*)(smem + tok * 128 + ((seg * 8) ^ ((tok & 15) * 8))) =
          Kg[(size_t)tok * 16 + seg];
    }
    const unsigned long long* Vg = (const unsigned long long*)(V8 + (size_t)b * 65536);
    for (int i = tid; i < 8192; i += 512) {
      int d = i >> 6, seg = i & 63;
      *(unsigned long long*)(smem + 65536 + d * 512 + ((seg * 8) ^ ((d & 15) * 8))) =
          Vg[(size_t)d * 64 + seg];
    }
  }
  // ---- init ----
  s_maskb[tid] = mav[b * 512 + tid] ? 1 : 0;
  {  // h0 -> U (step 0's h-buffer) — recurrent init: software RNE
    int idx = tid * 8;
    int a = idx >> 7, n0 = idx & 127;
    const float* hp = hid + (size_t)(b * 64 + a0 + a) * 128 + n0;
    short8 v;
#pragma unroll
    for (int j = 0; j < 8; ++j) v[j] = (short)f2bf(hp[j]);
    *(short8*)(s_bufU + a * 136 + n0) = v;
  }
  float c_reg[2][4], avl[2][4];
#pragma unroll
  for (int mt = 0; mt < 2; ++mt)
#pragma unroll
    for (int r = 0; r < 4; ++r) {
      int a = mt * 16 + quad * 4 + r;
      c_reg[mt][r] = ctx[(size_t)(b * 64 + a0 + a) * 128 + wave * 16 + l16];
      avl[mt][r] = (cav[b * 64 + a0 + a] != 0) ? 1.f : 0.f;
    }

  // ---- persistent register-cached weights (step-invariant) ----
  const int wrow = wave * 16 + l16;
  short8 rIH[4][4], rHH[4][4];
#pragma unroll
  for (int kt = 0; kt < 4; ++kt)
#pragma unroll
    for (int g = 0; g < 4; ++g) {
      rIH[kt][g] = *(const short8*)(WIHO + ((g * 128 + wrow) * 128 + kt * 32 + quad * 8));
      rHH[kt][g] = *(const short8*)(WHH + ((g * 128 + wrow) * 128 + kt * 32 + quad * 8));
    }
  short8 rWQ3[2];
#pragma unroll
  for (int kt = 0; kt < 2; ++kt)
    rWQ3[kt] = *(const short8*)(WQ3 + (wrow * 64 + kt * 32 + quad * 8));
  float rB4[4];
#pragma unroll
  for (int g = 0; g < 4; ++g) rB4[g] = B4p[g * 128 + wrow];
  const float rBQ3 = BQ3S[wrow];
  const float rB2 = b2[(wave & 3) * 16 + l16];

  // ---- fused-P7/P0 per-thread constants + register state ----
  const int p7_o = tid >> 3, p7_sub = tid & 7;
  const int p7_a = p7_o >> 1, p7_oi = p7_o & 1;
  const float mylnb = lnb[p7_oi];
  float myst = cf[(size_t)(b * 64 + a0 + p7_a) * 2 + p7_oi];

  __syncthreads();

  // per-lane mask flags: bit i set when token i*16+l16 is NOT available.
  unsigned mflags = 0;
#pragma unroll
  for (int i = 0; i < 32; ++i)
    if (!s_maskb[i * 16 + l16]) mflags |= (1u << i);

  // ---- initial h1 from initial state -> V (step 0's xb) ----
  {
    float other = __shfl_xor(myst, 8);
    float st0 = p7_oi ? other : myst;
    float st1 = p7_oi ? myst : other;
    int a = tid >> 4, n0 = (tid & 15) * 8;
    const float* wp = w1 + n0 * 2;
    const float* bp = b1 + n0;
    float x[8];
#pragma unroll
    for (int j = 0; j < 8; ++j)
      x[j] = fmaxf(fmaf(wp[j * 2], st0, fmaf(wp[j * 2 + 1], st1, bp[j])), 0.f);
    union { short8 s; unsigned u[4]; } v;
#pragma unroll
    for (int j = 0; j < 4; ++j) v.u[j] = cvtpk_bf16(x[j * 2], x[j * 2 + 1]);
    *(short8*)(s_bufV + a * 136 + n0) = v.s;
  }
  __syncthreads();

#pragma unroll 1
  for (int t = 0; t < T; ++t) {
    unsigned short* hb = (t & 1) ? s_bufV : s_bufU;  // holds h(t)
    unsigned short* xb = (t & 1) ? s_bufU : s_bufV;  // h1 | qf8 | h(t+1)

    // ---- P1: h2 = relu(h1 @ w2^T + b2)  M32 N64 K128 -> zone ----
    {
      int mt = wave >> 2, nt = wave & 3;
      f32x4 acc = splat4(rB2);
#pragma unroll
      for (int kt = 0; kt < 4; ++kt) {
        short8 a8 = *(const short8*)(xb + (mt * 16 + l16) * 136 + kt * 32 + quad * 8);
        short8 b8 = *(const short8*)(W2 + ((nt * 16 + l16) * 128 + kt * 32 + quad * 8));
        acc = mfma_bf16(a8, b8, acc);
      }
      unsigned pk01 = cvtpk_bf16(fmaxf(acc[0], 0.f), fmaxf(acc[1], 0.f));
      unsigned pk23 = cvtpk_bf16(fmaxf(acc[2], 0.f), fmaxf(acc[3], 0.f));
      unsigned short* hbp = s_h2 + (mt * 16 + quad * 4) * 72 + nt * 16 + l16;
      hbp[0] = (unsigned short)pk01;
      hbp[72] = (unsigned short)(pk01 >> 16);
      hbp[144] = (unsigned short)pk23;
      hbp[216] = (unsigned short)(pk23 >> 16);
    }
    __syncthreads();

    // ---- P3: q = h2 @ WQ3^T + bq3 -> fp8 in xb bytes (h1 dead) ----
    // wave nt==h produces exactly head h's q-columns -> no barrier before P4.
    unsigned char* s_q8 = (unsigned char*)xb;
    {
#pragma unroll
      for (int mt = 0; mt < 2; ++mt) {
        f32x4 acc = splat4(rBQ3);
#pragma unroll
        for (int kt = 0; kt < 2; ++kt) {
          short8 a8 = *(const short8*)(s_h2 + (mt * 16 + l16) * 72 + kt * 32 + quad * 8);
          acc = mfma_bf16(a8, rWQ3[kt], acc);
        }
#pragma unroll
        for (int r = 0; r < 4; ++r)
          s_q8[(mt * 16 + quad * 4 + r) * 136 + wave * 16 + l16] = f2fp8(acc[r]);
      }
    }
    __asm__ volatile("s_waitcnt lgkmcnt(0)" ::: "memory");
    __builtin_amdgcn_sched_barrier(0);

    // ---- P4: attention — swapped-operand MFMA, P in registers, prefetched ----
    {
      const int h = wave;
      const char* sKb = (const char*)smem;
      const char* sVrow = (const char*)(smem + 65536) + (h * 16 + l16) * 512;
      long qA[2];
#pragma unroll
      for (int mt = 0; mt < 2; ++mt)
        qA[mt] = (quad < 2)
                     ? *(const long*)(s_q8 + (mt * 16 + l16) * 136 + h * 16 + quad * 8)
                     : (quad == 2 ? 0xF8L : 0L);  // byte0 = fp8 -256
      const int koff = (h * 16 + quad * 8) ^ (l16 * 8);
      f32x4 O[2], L4[2];
      O[0] = zero4; O[1] = zero4; L4[0] = zero4; L4[1] = zero4;
      // prefetch chunk 0
      long vA_c = *(const long*)(sVrow + ((quad * 8) ^ (l16 * 8)));
      long kB_c0 = 0L, kB_c1 = 0L;
      if (quad < 2) {
        kB_c0 = *(const long*)(sKb + (size_t)l16 * 128 + koff);
        kB_c1 = *(const long*)(sKb + (size_t)(16 + l16) * 128 + koff);
      }
#pragma unroll 4
      for (int c = 0; c < 16; ++c) {
        long vA_n = 0L, kB_n0 = 0L, kB_n1 = 0L;
        if (c < 15) {
          vA_n = *(const long*)(sVrow + (((c + 1) * 32 + quad * 8) ^ (l16 * 8)));
          if (quad < 2) {
            kB_n0 = *(const long*)(sKb + (size_t)((c + 1) * 32 + l16) * 128 + koff);
            kB_n1 = *(const long*)(sKb + (size_t)((c + 1) * 32 + 16 + l16) * 128 + koff);
          }
        }
        long kB0 = kB_c0, kB1 = kB_c1;
        if (quad == 2) {
          kB0 = ((mflags >> (c * 2)) & 1u) ? 0x38L : 0L;      // fp8 1.0 flag
          kB1 = ((mflags >> (c * 2 + 1)) & 1u) ? 0x38L : 0L;
        }
        __builtin_amdgcn_s_setprio(1);
        f32x4 S2[2][2];
        S2[0][0] = mfma_fp8(kB0, qA[0], zero4);
        S2[0][1] = mfma_fp8(kB0, qA[1], zero4);
        S2[1][0] = mfma_fp8(kB1, qA[0], zero4);
        S2[1][1] = mfma_fp8(kB1, qA[1], zero4);
        __builtin_amdgcn_s_setprio(0);
        long pB[2];
#pragma unroll
        for (int mt = 0; mt < 2; ++mt) {
          unsigned w0 = (unsigned)__builtin_amdgcn_cvt_pk_fp8_f32(
              fexp2(S2[0][mt][0]), fexp2(S2[0][mt][1]), 0, false);
          w0 = (unsigned)__builtin_amdgcn_cvt_pk_fp8_f32(
              fexp2(S2[0][mt][2]), fexp2(S2[0][mt][3]), (int)w0, true);
          unsigned w1v = (unsigned)__builtin_amdgcn_cvt_pk_fp8_f32(
              fexp2(S2[1][mt][0]), fexp2(S2[1][mt][1]), 0, false);
          w1v = (unsigned)__builtin_amdgcn_cvt_pk_fp8_f32(
              fexp2(S2[1][mt][2]), fexp2(S2[1][mt][3]), (int)w1v, true);
          pB[mt] = (long)(((unsigned long long)w1v << 32) | (unsigned long long)w0);
        }
        __builtin_amdgcn_s_setprio(1);
        O[0] = mfma_fp8(vA_c, pB[0], O[0]);     // O^T: rows d-local, cols a
        L4[0] = mfma_fp8(kOnes, pB[0], L4[0]);
        O[1] = mfma_fp8(vA_c, pB[1], O[1]);
        L4[1] = mfma_fp8(kOnes, pB[1], L4[1]);
        __builtin_amdgcn_s_setprio(0);
        vA_c = vA_n; kB_c0 = kB_n0; kB_c1 = kB_n1;
      }
      // o -> bufB (within-step pack); O^T: d = h*16+quad*4+r, a = mt*16+l16
#pragma unroll
      for (int mt = 0; mt < 2; ++mt) {
        float o0 = O[mt][0] * frcp(L4[mt][0]);
        float o1 = O[mt][1] * frcp(L4[mt][1]);
        float o2 = O[mt][2] * frcp(L4[mt][2]);
        float o3 = O[mt][3] * frcp(L4[mt][3]);
        unsigned long long ow =
            ((unsigned long long)cvtpk_bf16(o2, o3) << 32) | cvtpk_bf16(o0, o1);
        *(unsigned long long*)(s_bufB + (mt * 16 + l16) * 136 + h * 16 + quad * 4) = ow;
      }
    }
    __syncthreads();

    // ---- P6: LSTM gates; reads h from hb + o from bufB, writes h(t+1) to
    // xb (qf8 dead; disjoint from all P6 reads -> no mid-barrier). ----
    {
      const int ni = wave;
      f32x4 gi[2], gf[2], gg[2], go[2];
#pragma unroll
      for (int mt = 0; mt < 2; ++mt) {
        gi[mt] = splat4(rB4[0]);
        gf[mt] = splat4(rB4[1]);
        gg[mt] = splat4(rB4[2]);
        go[mt] = splat4(rB4[3]);
      }
      __builtin_amdgcn_s_setprio(1);
#pragma unroll
      for (int kt = 0; kt < 4; ++kt)
#pragma unroll
        for (int mt = 0; mt < 2; ++mt) {
          short8 a8 = *(const short8*)(s_bufB + (mt * 16 + l16) * 136 + kt * 32 + quad * 8);
          gi[mt] = mfma_bf16(a8, rIH[kt][0], gi[mt]);
          gf[mt] = mfma_bf16(a8, rIH[kt][1], gf[mt]);
          gg[mt] = mfma_bf16(a8, rIH[kt][2], gg[mt]);
          go[mt] = mfma_bf16(a8, rIH[kt][3], go[mt]);
        }
#pragma unroll
      for (int kt = 0; kt < 4; ++kt)
#pragma unroll
        for (int mt = 0; mt < 2; ++mt) {
          short8 a8 = *(const short8*)(hb + (mt * 16 + l16) * 136 + kt * 32 + quad * 8);
          gi[mt] = mfma_bf16(a8, rHH[kt][0], gi[mt]);
          gf[mt] = mfma_bf16(a8, rHH[kt][1], gf[mt]);
          gg[mt] = mfma_bf16(a8, rHH[kt][2], gg[mt]);
          go[mt] = mfma_bf16(a8, rHH[kt][3], go[mt]);
        }
      __builtin_amdgcn_s_setprio(0);
#pragma unroll
      for (int mt = 0; mt < 2; ++mt)
#pragma unroll
        for (int r = 0; r < 4; ++r) {
          float iv = sigm(gi[mt][r]);
          float fv = sigm(gf[mt][r]);
          float gv = tanh_f(gg[mt][r]);
          float ov = sigm(go[mt][r]);
          float cn = fmaf(fv, c_reg[mt][r], iv * gv);
          float hv = ov * tanh_f(cn);
          int arow = mt * 16 + quad * 4 + r;
          float av = avl[mt][r];
          union { unsigned int u; float f; } ho;
          ho.u = ((unsigned int)hb[arow * 136 + ni * 16 + l16]) << 16;
          c_reg[mt][r] = av * cn + (1.f - av) * c_reg[mt][r];
          float hn = av * hv + (1.f - av) * ho.f;
          xb[arow * 136 + ni * 16 + l16] = f2bf(hn);  // recurrent: RNE
        }
    }
    __syncthreads();

    // ---- P7+P0 fused: state += h @ lin_w^T + lin_b; emit; next h1 ----
    {
      const unsigned short* hp = xb + p7_a * 136 + p7_sub * 16;
      const float* lw = lnw + p7_oi * 128 + p7_sub * 16;
      short8 h0 = *(const short8*)hp;
      short8 h1 = *(const short8*)(hp + 8);
      float acc = 0.f;
#pragma unroll
      for (int k = 0; k < 8; ++k) {
        union { unsigned int u; float f; } hv;
        hv.u = ((unsigned int)(unsigned short)h0[k]) << 16;
        acc = fmaf(hv.f, lw[k], acc);
      }
#pragma unroll
      for (int k = 0; k < 8; ++k) {
        union { unsigned int u; float f; } hv;
        hv.u = ((unsigned int)(unsigned short)h1[k]) << 16;
        acc = fmaf(hv.f, lw[8 + k], acc);
      }
      acc += __shfl_xor(acc, 4);
      acc += __shfl_xor(acc, 2);
      acc += __shfl_xor(acc, 1);
      float ns = myst + acc + mylnb;
      myst = ns;
      if (p7_sub == 0)
        out[((size_t)(b * 64 + a0 + p7_a) * T + t) * 2 + p7_oi] = ns;
      // P0: h1(t+1) = relu(state @ w1^T + b1) -> hb (h(t) dead)
      float other = __shfl_xor(ns, 8);
      float st0 = p7_oi ? other : ns;
      float st1 = p7_oi ? ns : other;
      int a = tid >> 4, n0 = (tid & 15) * 8;
      const float* wp = w1 + n0 * 2;
      const float* bp = b1 + n0;
      float x[8];
#pragma unroll
      for (int j = 0; j < 8; ++j)
        x[j] = fmaxf(fmaf(wp[j * 2], st0, fmaf(wp[j * 2 + 1], st1, bp[j])), 0.f);
      union { short8 s; unsigned u[4]; } v;
#pragma unroll
      for (int j = 0; j < 4; ++j) v.u[j] = cvtpk_bf16(x[j * 2], x[j * 2 + 1]);
      *(short8*)(hb + a * 136 + n0) = v.s;
    }
    __syncthreads();
  }
}

// ---------------------------------------------------------------- launch ----
extern "C" void kernel_launch(void* const* d_in, const int* in_sizes, int n_in,
                              void* d_out, int out_size, void* d_ws, size_t ws_size,
                              hipStream_t stream) {
  (void)in_sizes; (void)n_in; (void)out_size; (void)ws_size;
  const float* cf = (const float*)d_in[0];
  const int* cav = (const int*)d_in[1];
  const float* hid = (const float*)d_in[2];
  const float* ctx = (const float*)d_in[3];
  const float* emb = (const float*)d_in[4];
  const int* mav = (const int*)d_in[5];
  const int* ntp = (const int*)d_in[6];
  const float* w1 = (const float*)d_in[7];
  const float* b1 = (const float*)d_in[8];
  const float* w2 = (const float*)d_in[9];
  const float* b2 = (const float*)d_in[10];
  const float* w3 = (const float*)d_in[11];
  const float* b3 = (const float*)d_in[12];
  const float* wq = (const float*)d_in[13];
  const float* bq = (const float*)d_in[14];
  const float* wk = (const float*)d_in[15];
  const float* bk = (const float*)d_in[16];
  const float* wv = (const float*)d_in[17];
  const float* bv = (const float*)d_in[18];
  const float* wo = (const float*)d_in[19];
  const float* bo = (const float*)d_in[20];
  const float* wih = (const float*)d_in[21];  // w_ih
  const float* whh = (const float*)d_in[22];  // w_hh
  const float* bih = (const float*)d_in[23];  // b_ih
  const float* bhh = (const float*)d_in[24];  // b_hh
  const float* lnw = (const float*)d_in[25];
  const float* lnb = (const float*)d_in[26];

  char* ws = (char*)d_ws;
  unsigned char* K8 = (unsigned char*)(ws + 0);         // 8,388,608
  unsigned char* V8 = (unsigned char*)(ws + 8388608);   // 8,388,608
  unsigned short* W2s = (unsigned short*)(ws + 16777216);   // 16,384 B
  unsigned short* WQ3s = (unsigned short*)(ws + 16793600);  // 16,384 B
  unsigned short* WIHOs = (unsigned short*)(ws + 16809984); // 131,072 B
  unsigned short* WHHs = (unsigned short*)(ws + 16941056);  // 131,072 B
  float* B4p = (float*)(ws + 17072128);                     // 2,048 B
  float* BQ3S = (float*)(ws + 17074176);                    // 512 B

  (void)hipFuncSetAttribute((const void*)prep_kernel,
                            hipFuncAttributeMaxDynamicSharedMemorySize, 69632);
  (void)hipFuncSetAttribute((const void*)decoder_kernel,
                            hipFuncAttributeMaxDynamicSharedMemorySize, 162560);

  prep_kernel<<<682, 512, 69632, stream>>>(
      emb, wk, bk, wv, bv, w2, whh, wih, wo, wq, w3, b3, bq, bo, bih, bhh,
      K8, V8, W2s, WHHs, WIHOs, WQ3s, B4p, BQ3S);
  decoder_kernel<<<256, 512, 162560, stream>>>(
      cf, cav, hid, ctx, mav, ntp, w1, b1, b2, K8, V8, W2s, WQ3s, WIHOs, WHHs,
      B4p, BQ3S, lnw, lnb, (float*)d_out);
}